// Round 7
// baseline (460.724 us; speedup 1.0000x reference)
//
#include <hip/hip_runtime.h>
#include <hip/hip_bf16.h>

// Problem constants
#define BSZ 16
#define LP 128
#define LR 1024
#define DD 128
#define DG 640
#define KH 7
#define SPLITK 4

typedef __bf16 bf16x8 __attribute__((ext_vector_type(8)));
typedef __bf16 bf16x4v __attribute__((ext_vector_type(4)));
typedef float f32x4 __attribute__((ext_vector_type(4)));
typedef unsigned int uint32;

// ---------------------------------------------------------------------------
// MFMA core, bf16 A and B: 128(M) x 64(N) tile, BK=64, 4 waves (each 32x64),
// DEPTH-2 prefetch with two named 24-VGPR staging sets (x/y): the ds_write
// of set x waits on loads issued two compute phases (~900 cy) earlier.
// Same 2 barriers per K-step as depth-1; only the register distance changes.
// ---------------------------------------------------------------------------
__device__ __forceinline__ void mfma_core_n64(
    const ushort* __restrict__ Ab, int lda,
    const ushort* __restrict__ Bb, int ldb,
    int m0, int n0, int kStart, int kEnd, f32x4 (&acc)[2][4]) {
  __shared__ __align__(16) ushort As[128 * 72];
  __shared__ __align__(16) ushort Bs[64 * 72];
  int t = threadIdx.x;
  int wave = t >> 6, lane = t & 63;
  int quad = lane >> 4, l16 = lane & 15;
  int wm = wave * 32;
  int r1 = t >> 2, o1 = (t & 3) * 16;

  int4 xa0, xa1, xa2, xa3, xb0, xb1;
  int4 ya0, ya1, ya2, ya3, yb0, yb1;

  auto load_x = [&](int k0) {
    xa0 = *(const int4*)(Ab + (size_t)(m0 + r1) * lda + k0 + o1);
    xa1 = *(const int4*)(Ab + (size_t)(m0 + r1) * lda + k0 + o1 + 8);
    xa2 = *(const int4*)(Ab + (size_t)(m0 + r1 + 64) * lda + k0 + o1);
    xa3 = *(const int4*)(Ab + (size_t)(m0 + r1 + 64) * lda + k0 + o1 + 8);
    xb0 = *(const int4*)(Bb + (size_t)(n0 + r1) * ldb + k0 + o1);
    xb1 = *(const int4*)(Bb + (size_t)(n0 + r1) * ldb + k0 + o1 + 8);
  };
  auto load_y = [&](int k0) {
    ya0 = *(const int4*)(Ab + (size_t)(m0 + r1) * lda + k0 + o1);
    ya1 = *(const int4*)(Ab + (size_t)(m0 + r1) * lda + k0 + o1 + 8);
    ya2 = *(const int4*)(Ab + (size_t)(m0 + r1 + 64) * lda + k0 + o1);
    ya3 = *(const int4*)(Ab + (size_t)(m0 + r1 + 64) * lda + k0 + o1 + 8);
    yb0 = *(const int4*)(Bb + (size_t)(n0 + r1) * ldb + k0 + o1);
    yb1 = *(const int4*)(Bb + (size_t)(n0 + r1) * ldb + k0 + o1 + 8);
  };
  auto stage = [&](int4 a0, int4 a1, int4 a2, int4 a3, int4 b0, int4 b1) {
    *(int4*)&As[r1 * 72 + o1] = a0;
    *(int4*)&As[r1 * 72 + o1 + 8] = a1;
    *(int4*)&As[(r1 + 64) * 72 + o1] = a2;
    *(int4*)&As[(r1 + 64) * 72 + o1 + 8] = a3;
    *(int4*)&Bs[r1 * 72 + o1] = b0;
    *(int4*)&Bs[r1 * 72 + o1 + 8] = b1;
  };
  auto compute = [&]() {
    #pragma unroll
    for (int kc = 0; kc < 2; ++kc) {
      bf16x8 af[2], bfr[4];
      #pragma unroll
      for (int fi = 0; fi < 2; ++fi)
        af[fi] = *(const bf16x8*)&As[(wm + fi * 16 + l16) * 72 + kc * 32 + quad * 8];
      #pragma unroll
      for (int fj = 0; fj < 4; ++fj)
        bfr[fj] = *(const bf16x8*)&Bs[(fj * 16 + l16) * 72 + kc * 32 + quad * 8];
      #pragma unroll
      for (int fi = 0; fi < 2; ++fi)
        #pragma unroll
        for (int fj = 0; fj < 4; ++fj)
          acc[fi][fj] = __builtin_amdgcn_mfma_f32_16x16x32_bf16(
              af[fi], bfr[fj], acc[fi][fj], 0, 0, 0);
    }
  };

  int nIter = (kEnd - kStart) >> 6;
  load_x(kStart);
  if (nIter > 1) load_y(kStart + 64);
  for (int it = 0; it < nIter; it += 2) {
    __syncthreads();                       // prev compute done with LDS
    stage(xa0, xa1, xa2, xa3, xb0, xb1);   // waits only on x-loads (2 phases old)
    __syncthreads();
    if (it + 2 < nIter) load_x(kStart + (it + 2) * 64);
    compute();
    if (it + 1 < nIter) {
      __syncthreads();
      stage(ya0, ya1, ya2, ya3, yb0, yb1);
      __syncthreads();
      if (it + 3 < nIter) load_y(kStart + (it + 3) * 64);
      compute();
    }
  }
}

// ---------------------------------------------------------------------------
// agg core: A built in-register from packed adjacency bits, 128(M)x64(N),
// BK=64, DEPTH-2 prefetch (two 9-VGPR staging sets). LDS = 10KB.
// acc[c][d] += sum_r Ahat[r,c] * Xt[d][bcol + r]
// ---------------------------------------------------------------------------
__device__ __forceinline__ void agg_core_n64(
    const uint32* __restrict__ pb, int L,
    const ushort* __restrict__ Bb, int ldb,
    int m0, int n0, f32x4 (&acc)[2][4]) {
  __shared__ __align__(16) ushort Bs[64 * 72];
  __shared__ uint32 Aw[2][128];
  int t = threadIdx.x;
  int wave = t >> 6, lane = t & 63;
  int quad = lane >> 4, l16 = lane & 15;
  int wm = wave * 32;
  int r1 = t >> 2, o1 = (t & 3) * 16;
  int half = t >> 7, cc = t & 127;

  int4 xb0, xb1; uint32 xw;
  int4 yb0, yb1; uint32 yw;

  auto load_x = [&](int k0) {
    xb0 = *(const int4*)(Bb + (size_t)(n0 + r1) * ldb + k0 + o1);
    xb1 = *(const int4*)(Bb + (size_t)(n0 + r1) * ldb + k0 + o1 + 8);
    xw = pb[(size_t)((k0 >> 5) + half) * L + m0 + cc];
  };
  auto load_y = [&](int k0) {
    yb0 = *(const int4*)(Bb + (size_t)(n0 + r1) * ldb + k0 + o1);
    yb1 = *(const int4*)(Bb + (size_t)(n0 + r1) * ldb + k0 + o1 + 8);
    yw = pb[(size_t)((k0 >> 5) + half) * L + m0 + cc];
  };
  auto stage = [&](int4 b0, int4 b1, uint32 w) {
    *(int4*)&Bs[r1 * 72 + o1] = b0;
    *(int4*)&Bs[r1 * 72 + o1 + 8] = b1;
    Aw[half][cc] = w;
  };
  auto compute = [&]() {
    #pragma unroll
    for (int kc = 0; kc < 2; ++kc) {
      bf16x8 af[2], bfr[4];
      #pragma unroll
      for (int fj = 0; fj < 4; ++fj)
        bfr[fj] = *(const bf16x8*)&Bs[(fj * 16 + l16) * 72 + kc * 32 + quad * 8];
      #pragma unroll
      for (int fi = 0; fi < 2; ++fi) {
        uint32 bits = (Aw[kc][wm + fi * 16 + l16] >> (quad * 8)) & 0xffu;
        int4 p;
        p.x = (int)((((bits >> 0) & 1) ? 0x3F80u : 0u) | (((bits >> 1) & 1) ? 0x3F800000u : 0u));
        p.y = (int)((((bits >> 2) & 1) ? 0x3F80u : 0u) | (((bits >> 3) & 1) ? 0x3F800000u : 0u));
        p.z = (int)((((bits >> 4) & 1) ? 0x3F80u : 0u) | (((bits >> 5) & 1) ? 0x3F800000u : 0u));
        p.w = (int)((((bits >> 6) & 1) ? 0x3F80u : 0u) | (((bits >> 7) & 1) ? 0x3F800000u : 0u));
        af[fi] = *(bf16x8*)&p;
      }
      #pragma unroll
      for (int fi = 0; fi < 2; ++fi)
        #pragma unroll
        for (int fj = 0; fj < 4; ++fj)
          acc[fi][fj] = __builtin_amdgcn_mfma_f32_16x16x32_bf16(
              af[fi], bfr[fj], acc[fi][fj], 0, 0, 0);
    }
  };

  int nIter = L >> 6;
  load_x(0);
  if (nIter > 1) load_y(64);
  for (int it = 0; it < nIter; it += 2) {
    __syncthreads();
    stage(xb0, xb1, xw);
    __syncthreads();
    if (it + 2 < nIter) load_x((it + 2) * 64);
    compute();
    if (it + 1 < nIter) {
      __syncthreads();
      stage(yb0, yb1, yw);
      __syncthreads();
      if (it + 3 < nIter) load_y((it + 3) * 64);
      compute();
    }
  }
}

// ---------------------------------------------------------------------------
// MFMA core, f32 A (converted to bf16 during staging), 64(M)x128(N), BK=64,
// depth-1 prefetch. Used only by pre_gemm (r6 verbatim).
// ---------------------------------------------------------------------------
__device__ __forceinline__ void mfma_core_f32_m64(
    const float* __restrict__ Af, int lda,
    const ushort* __restrict__ Bb, int ldb,
    int m0, int kStart, int kEnd, f32x4 (&acc)[2][4]) {
  __shared__ __align__(16) ushort As[64 * 72];
  __shared__ __align__(16) ushort Bs[128 * 72];
  int t = threadIdx.x;
  int wave = t >> 6, lane = t & 63;
  int quad = lane >> 4, l16 = lane & 15;
  int wm = (wave >> 1) * 32, wn = (wave & 1) * 64;
  int r1 = t >> 2, o1 = (t & 3) * 16;

  int4 b00, b01, b10, b11;
  float4 af32[4];

  auto load_k = [&](int k0) {
    b00 = *(const int4*)(Bb + (size_t)r1 * ldb + k0 + o1);
    b01 = *(const int4*)(Bb + (size_t)r1 * ldb + k0 + o1 + 8);
    b10 = *(const int4*)(Bb + (size_t)(r1 + 64) * ldb + k0 + o1);
    b11 = *(const int4*)(Bb + (size_t)(r1 + 64) * ldb + k0 + o1 + 8);
    #pragma unroll
    for (int s = 0; s < 4; ++s) {
      int idx = t + s * 256;
      int row = idx >> 4, c4 = (idx & 15) * 4;
      af32[s] = *(const float4*)(Af + (size_t)(m0 + row) * lda + k0 + c4);
    }
  };

  load_k(kStart);
  for (int k0 = kStart; k0 < kEnd; k0 += 64) {
    __syncthreads();
    #pragma unroll
    for (int s = 0; s < 4; ++s) {
      int idx = t + s * 256;
      int row = idx >> 4, c4 = (idx & 15) * 4;
      ushort4 u; __bf16 h;
      h = (__bf16)af32[s].x; u.x = *(ushort*)&h;
      h = (__bf16)af32[s].y; u.y = *(ushort*)&h;
      h = (__bf16)af32[s].z; u.z = *(ushort*)&h;
      h = (__bf16)af32[s].w; u.w = *(ushort*)&h;
      *(ushort4*)&As[row * 72 + c4] = u;
    }
    *(int4*)&Bs[r1 * 72 + o1] = b00;
    *(int4*)&Bs[r1 * 72 + o1 + 8] = b01;
    *(int4*)&Bs[(r1 + 64) * 72 + o1] = b10;
    *(int4*)&Bs[(r1 + 64) * 72 + o1 + 8] = b11;
    __syncthreads();
    if (k0 + 64 < kEnd) load_k(k0 + 64);  // prefetch under compute
    #pragma unroll
    for (int kc = 0; kc < 2; ++kc) {
      bf16x8 af[2], bfr[4];
      #pragma unroll
      for (int fi = 0; fi < 2; ++fi)
        af[fi] = *(const bf16x8*)&As[(wm + fi * 16 + l16) * 72 + kc * 32 + quad * 8];
      #pragma unroll
      for (int fj = 0; fj < 4; ++fj)
        bfr[fj] = *(const bf16x8*)&Bs[(wn + fj * 16 + l16) * 72 + kc * 32 + quad * 8];
      #pragma unroll
      for (int fi = 0; fi < 2; ++fi)
        #pragma unroll
        for (int fj = 0; fj < 4; ++fj)
          acc[fi][fj] = __builtin_amdgcn_mfma_f32_16x16x32_bf16(
              af[fi], bfr[fj], acc[fi][fj], 0, 0, 0);
    }
  }
}

// ---------------------------------------------------------------------------
// prep_weights: all weight conversions/transposes in one dispatch.
// grid (560, 1, 8)
// ---------------------------------------------------------------------------
__device__ __forceinline__ void tr_tile(const float* __restrict__ src,
                                        __bf16* __restrict__ dst,
                                        int R, int C, int cb, int rb, int t) {
  __shared__ float T[32][33];
  int r0 = rb * 32, c0 = cb * 32;
  #pragma unroll
  for (int s = 0; s < 4; ++s) {
    int idx = t + s * 256;
    int r = idx >> 5, c = idx & 31;
    T[r][c] = src[(size_t)(r0 + r) * C + c0 + c];
  }
  __syncthreads();
  #pragma unroll
  for (int s = 0; s < 4; ++s) {
    int idx = t + s * 256;
    int c = idx >> 5, r = idx & 31;
    dst[(size_t)(c0 + c) * R + r0 + r] = (__bf16)T[r][c];
  }
}

__global__ __launch_bounds__(256) void prep_weights(
    const float* __restrict__ Wppep, const float* __restrict__ Wppro,
    const float* __restrict__ Wg1p, const float* __restrict__ Wg2p,
    const float* __restrict__ Wg1r, const float* __restrict__ Wg2r,
    const float* __restrict__ Wtp, const float* __restrict__ Wtr,
    __bf16* __restrict__ WppTp, __bf16* __restrict__ WppTr,
    __bf16* __restrict__ Wg1Tp, __bf16* __restrict__ Wg2Tp,
    __bf16* __restrict__ Wg1Tr, __bf16* __restrict__ Wg2Tr,
    __bf16* __restrict__ WtBp, __bf16* __restrict__ WtBr) {
  int z = blockIdx.z, bx = blockIdx.x, t = threadIdx.x;
  if (z < 2) {
    if (bx >= 128) return;
    tr_tile(z ? Wppro : Wppep, z ? WppTr : WppTp, 1024, 128, bx % 4, bx / 4, t);
  } else if (z < 6) {
    if (bx >= 400) return;
    const float* src = (z == 2) ? Wg1p : (z == 3) ? Wg2p : (z == 4) ? Wg1r : Wg2r;
    __bf16* dst = (z == 2) ? Wg1Tp : (z == 3) ? Wg2Tp : (z == 4) ? Wg1Tr : Wg2Tr;
    tr_tile(src, dst, 640, 640, bx % 20, bx / 20, t);
  } else {
    if (bx >= 560) return;
    const float* src = (z == 6) ? Wtp : Wtr;
    __bf16* dst = (z == 6) ? WtBp : WtBr;
    int i = bx * 256 + t;  // < 143360 float4s
    float4 v = ((const float4*)src)[i];
    bf16x4v o;
    o.x = (__bf16)v.x; o.y = (__bf16)v.y; o.z = (__bf16)v.z; o.w = (__bf16)v.w;
    ((bf16x4v*)dst)[i] = o;
  }
}

// ---------------------------------------------------------------------------
// prep_pack merged: grid (4, 32, 17). z<16: pro (b=z, rw=y, c=x*256+t);
// z==16: pep (b=y<16, rw=x, c=t<128).
// ---------------------------------------------------------------------------
__global__ __launch_bounds__(256) void prep_pack_merged(
    const float* __restrict__ adjP, const float* __restrict__ adjR,
    uint32* __restrict__ packedP, uint32* __restrict__ packedR,
    float* __restrict__ degP, float* __restrict__ degR) {
  int t = threadIdx.x;
  const float* adj; uint32* packed; float* deg;
  int b, rw, c, L;
  if (blockIdx.z < 16) {
    L = LR; b = blockIdx.z; rw = blockIdx.y; c = blockIdx.x * 256 + t;
    adj = adjR; packed = packedR; deg = degR;
  } else {
    L = LP; b = blockIdx.y; rw = blockIdx.x; c = t;
    if (b >= 16 || c >= LP) return;
    adj = adjP; packed = packedP; deg = degP;
  }
  const float* adjB = adj + (size_t)b * L * L;
  uint32 w = 0;
  int rbase = rw * 32;
  #pragma unroll 8
  for (int j = 0; j < 32; ++j) {
    float a = adjB[(size_t)(rbase + j) * L + c];
    if (a != 0.f || (rbase + j) == c) w |= (1u << j);
  }
  packed[((size_t)b * (L >> 5) + rw) * L + c] = w;
  atomicAdd(deg + b * L + c, (float)__popc(w));
}

// ---------------------------------------------------------------------------
// pre_gemm merged (split-K pretrain partials): grid (288, SPLITK).
// bx<32: pep m-block bx (64 rows each); else pro m-block bx-32. by = k-slice.
// ---------------------------------------------------------------------------
__global__ __launch_bounds__(256) void pre_gemm(
    const float* __restrict__ XpP, const float* __restrict__ XpR,
    const __bf16* __restrict__ WppTp, const __bf16* __restrict__ WppTr,
    float* __restrict__ partP, float* __restrict__ partR) {
  int bx = blockIdx.x, s = blockIdx.y;
  int pep = bx < (BSZ * LP / 64);
  int m0 = (pep ? bx : bx - BSZ * LP / 64) * 64;
  const float* A = pep ? XpP : XpR;
  const ushort* B = (const ushort*)(pep ? WppTp : WppTr);
  int BL = pep ? BSZ * LP : BSZ * LR;
  float* part = (pep ? partP : partR) + (size_t)s * BL * DD;

  f32x4 acc[2][4];
  #pragma unroll
  for (int i = 0; i < 2; ++i)
    #pragma unroll
    for (int j = 0; j < 4; ++j) acc[i][j] = (f32x4){0.f, 0.f, 0.f, 0.f};
  mfma_core_f32_m64(A, 1024, B, 1024, m0, s * (1024 / SPLITK),
                    (s + 1) * (1024 / SPLITK), acc);

  int t = threadIdx.x;
  int wave = t >> 6, lane = t & 63;
  int quad = lane >> 4, l16 = lane & 15;
  int wm = (wave >> 1) * 32, wn = (wave & 1) * 64;
  #pragma unroll
  for (int fi = 0; fi < 2; ++fi)
    #pragma unroll
    for (int r = 0; r < 4; ++r) {
      int m = m0 + wm + fi * 16 + quad * 4 + r;
      #pragma unroll
      for (int fj = 0; fj < 4; ++fj) {
        int n = wn + fj * 16 + l16;
        part[(size_t)m * DD + n] = acc[fi][fj][r];
      }
    }
}

// ---------------------------------------------------------------------------
// Encoder merged: embeddings + dense matmul + pretrain-partial reduce.
// grid (BLp + BLr, 128 threads)
// ---------------------------------------------------------------------------
__global__ __launch_bounds__(128) void encoder_merged(
    const int* __restrict__ xsP, const int* __restrict__ xssP,
    const int* __restrict__ x2P, const float* __restrict__ xdP,
    const float* __restrict__ WdP, const float* __restrict__ bdP,
    const float* __restrict__ maskP, const float* __restrict__ partP,
    const float* __restrict__ bppP, __bf16* __restrict__ encP,
    const int* __restrict__ xsR, const int* __restrict__ xssR,
    const int* __restrict__ x2R, const float* __restrict__ xdR,
    const float* __restrict__ WdR, const float* __restrict__ bdR,
    const float* __restrict__ maskR, const float* __restrict__ partR,
    const float* __restrict__ bppR, __bf16* __restrict__ encR,
    const float* __restrict__ Eseq, const float* __restrict__ Ess,
    const float* __restrict__ Etwo) {
  int gw = blockIdx.x;
  int t = threadIdx.x;
  int pep = gw < BSZ * LP;
  int row = pep ? gw : gw - BSZ * LP;
  int BL = pep ? BSZ * LP : BSZ * LR;
  int Kd = pep ? 3 : 23;
  const int* xs = pep ? xsP : xsR;
  const int* xss = pep ? xssP : xssR;
  const int* x2 = pep ? x2P : x2R;
  const float* xd = pep ? xdP : xdR;
  const float* Wd = pep ? WdP : WdR;
  const float* bd = pep ? bdP : bdR;
  const float* mask = pep ? maskP : maskR;
  const float* part = pep ? partP : partR;
  const float* bpp = pep ? bppP : bppR;
  __bf16* enc = pep ? encP : encR;

  float m = mask[row];
  int i0 = xs[row], i1 = xss[row], i2 = x2[row];
  __bf16* e = enc + (size_t)row * DG;
  e[t]        = (__bf16)(Eseq[i0 * DD + t] * m);
  e[DD + t]   = (__bf16)(Ess[i1 * DD + t] * m);
  e[2*DD + t] = (__bf16)(Etwo[i2 * DD + t] * m);
  float acc = bd[t];
  const float* xr = xd + (size_t)row * Kd;
  for (int i = 0; i < Kd; ++i) acc = fmaf(xr[i], Wd[i * DD + t], acc);
  e[3*DD + t] = (__bf16)(acc * m);
  // pretrain reduce -> cols 512..639
  float p = bpp[t];
  #pragma unroll
  for (int s = 0; s < SPLITK; ++s)
    p += part[(size_t)s * BL * DD + (size_t)row * DD + t];
  e[4*DD + t] = (__bf16)(p * m);
}

// ---------------------------------------------------------------------------
// linT merged: bufAT[d][row] = rsqrt(deg[row]) * sum_k src[row][k] * Wg[k][d]
// grid (288, 5): bx<32 pep n-block (64 rows each), else pro. by = m-block (d).
// ---------------------------------------------------------------------------
__global__ __launch_bounds__(256) void linT_merged(
    const __bf16* __restrict__ WgTp, const __bf16* __restrict__ srcP,
    const float* __restrict__ degP, __bf16* __restrict__ dstP,
    const __bf16* __restrict__ WgTr, const __bf16* __restrict__ srcR,
    const float* __restrict__ degR, __bf16* __restrict__ dstR) {
  int bx = blockIdx.x;
  int pep = bx < (BSZ * LP / 64);
  int n0 = (pep ? bx : bx - BSZ * LP / 64) * 64;
  int m0 = blockIdx.y * 128;
  int BL = pep ? BSZ * LP : BSZ * LR;
  const ushort* A = (const ushort*)(pep ? WgTp : WgTr);
  const ushort* B = (const ushort*)(pep ? srcP : srcR);
  const float* deg = pep ? degP : degR;
  __bf16* dst = pep ? dstP : dstR;

  f32x4 acc[2][4];
  #pragma unroll
  for (int i = 0; i < 2; ++i)
    #pragma unroll
    for (int j = 0; j < 4; ++j) acc[i][j] = (f32x4){0.f, 0.f, 0.f, 0.f};
  mfma_core_n64(A, DG, B, DG, m0, n0, 0, DG, acc);

  int t = threadIdx.x;
  int wave = t >> 6, lane = t & 63;
  int quad = lane >> 4, l16 = lane & 15;
  int wm = wave * 32;
  #pragma unroll
  for (int fi = 0; fi < 2; ++fi)
    #pragma unroll
    for (int r = 0; r < 4; ++r) {
      int m = m0 + wm + fi * 16 + quad * 4 + r;
      #pragma unroll
      for (int fj = 0; fj < 4; ++fj) {
        int n = n0 + fj * 16 + l16;
        dst[(size_t)m * BL + n] = (__bf16)(acc[fi][fj][r] * rsqrtf(deg[n]));
      }
    }
}

// ---------------------------------------------------------------------------
// agg merged, XCD-aware grid: (160, 9).
// bx encodes (b = bx/10, n0 = (bx%10)*64). by==0: pep (m0=0); else pro
// m-block by-1. Same-(b,n0) blocks differ by 160 (160%8==0) -> same XCD.
// Y[b,c,d] = relu(rsqrt(deg)*acc + bias[d] (+encE)) * (mask?)
// ---------------------------------------------------------------------------
__global__ __launch_bounds__(256) void agg_merged(
    const uint32* __restrict__ packedP, const __bf16* __restrict__ XtP,
    const float* __restrict__ degP, const float* __restrict__ biasP,
    const __bf16* __restrict__ encEP, const float* __restrict__ maskP,
    __bf16* __restrict__ YP,
    const uint32* __restrict__ packedR, const __bf16* __restrict__ XtR,
    const float* __restrict__ degR, const float* __restrict__ biasR,
    const __bf16* __restrict__ encER, const float* __restrict__ maskR,
    __bf16* __restrict__ YR) {
  int bx = blockIdx.x;
  int b = bx / 10;
  int n0 = (bx % 10) * 64;
  int pep = (blockIdx.y == 0);
  int L = pep ? LP : LR;
  int BL = BSZ * L;
  int m0 = pep ? 0 : (blockIdx.y - 1) * 128;
  const uint32* pb = (pep ? packedP : packedR) + (size_t)b * (L >> 5) * L;
  const ushort* Bb = (const ushort*)(pep ? XtP : XtR) + (size_t)b * L;
  const float* deg = pep ? degP : degR;
  const float* bias = pep ? biasP : biasR;
  const __bf16* encE = pep ? encEP : encER;
  const float* mask = pep ? maskP : maskR;
  __bf16* Y = pep ? YP : YR;

  f32x4 acc[2][4];
  #pragma unroll
  for (int i = 0; i < 2; ++i)
    #pragma unroll
    for (int j = 0; j < 4; ++j) acc[i][j] = (f32x4){0.f, 0.f, 0.f, 0.f};
  agg_core_n64(pb, L, Bb, BL, m0, n0, acc);

  int t = threadIdx.x;
  int wave = t >> 6, lane = t & 63;
  int quad = lane >> 4, l16 = lane & 15;
  int wm = wave * 32;
  int gRow = b * L;
  #pragma unroll
  for (int fi = 0; fi < 2; ++fi)
    #pragma unroll
    for (int r = 0; r < 4; ++r) {
      int m = m0 + wm + fi * 16 + quad * 4 + r;
      int gi = gRow + m;
      float di = rsqrtf(deg[gi]);
      float rm = mask ? mask[gi] : 1.f;
      #pragma unroll
      for (int fj = 0; fj < 4; ++fj) {
        int n = n0 + fj * 16 + l16;
        float v = acc[fi][fj][r] * di + bias[n];
        if (encE) v += (float)encE[(size_t)gi * DG + n];
        v = fmaxf(v, 0.f);
        v *= rm;
        Y[(size_t)gi * DG + n] = (__bf16)v;
      }
    }
}

// ---------------------------------------------------------------------------
// fct merged: grid (16, 7, 18). bz<16: pro (b=bz, n0=bx*64 over LR);
// bz>=16: pep (chunk=(bz-16)*16+bx over BLp flattened). out f32.
// ---------------------------------------------------------------------------
__global__ __launch_bounds__(256) void fct_merged(
    const __bf16* __restrict__ WtBp, const float* __restrict__ btp,
    const __bf16* __restrict__ Yp, float* __restrict__ outP,
    const __bf16* __restrict__ WtBr, const float* __restrict__ btr,
    const __bf16* __restrict__ Yr, float* __restrict__ outR) {
  int kh = blockIdx.y;
  int pro = (blockIdx.z < 16);
  const ushort* A;
  const ushort* B;
  const float* bt;
  int n0;
  if (pro) {
    A = (const ushort*)(WtBr + (size_t)kh * DD * DG);
    B = (const ushort*)(Yr + (size_t)blockIdx.z * LR * DG);
    bt = btr;
    n0 = blockIdx.x * 64;
  } else {
    A = (const ushort*)(WtBp + (size_t)kh * DD * DG);
    B = (const ushort*)Yp;
    bt = btp;
    n0 = ((blockIdx.z - 16) * 16 + blockIdx.x) * 64;
  }

  f32x4 acc[2][4];
  #pragma unroll
  for (int i = 0; i < 2; ++i)
    #pragma unroll
    for (int j = 0; j < 4; ++j) acc[i][j] = (f32x4){0.f, 0.f, 0.f, 0.f};
  mfma_core_n64(A, DG, B, DG, 0, n0, 0, DG, acc);

  int t = threadIdx.x;
  int wave = t >> 6, lane = t & 63;
  int quad = lane >> 4, l16 = lane & 15;
  int wm = wave * 32;
  #pragma unroll
  for (int fi = 0; fi < 2; ++fi)
    #pragma unroll
    for (int r = 0; r < 4; ++r) {
      int m = wm + fi * 16 + quad * 4 + r;
      float bb = bt[kh * DD + m];
      #pragma unroll
      for (int fj = 0; fj < 4; ++fj) {
        int n = n0 + fj * 16 + l16;
        float v = fmaxf(acc[fi][fj][r] + bb, 0.f);
        if (pro) {
          outR[((size_t)(kh * BSZ + blockIdx.z) * DD + m) * LR + n] = v;
        } else {
          int b = n >> 7, l = n & 127;
          outP[((size_t)(kh * BSZ + b) * DD + m) * LP + l] = v;
        }
      }
    }
}

// ---------------------------------------------------------------------------
extern "C" void kernel_launch(void* const* d_in, const int* in_sizes, int n_in,
                              void* d_out, int out_size, void* d_ws, size_t ws_size,
                              hipStream_t stream) {
  const int*   x_pep          = (const int*)d_in[0];
  const int*   x_ss_pep       = (const int*)d_in[1];
  const int*   x_2_pep        = (const int*)d_in[2];
  const float* x_dense_pep    = (const float*)d_in[3];
  const float* x_pretrain_pep = (const float*)d_in[4];
  const int*   x_pro          = (const int*)d_in[5];
  const int*   x_ss_pro       = (const int*)d_in[6];
  const int*   x_2_pro        = (const int*)d_in[7];
  const float* x_dense_pro    = (const float*)d_in[8];
  const float* x_pretrain_pro = (const float*)d_in[9];
  const float* x_edge_pep     = (const float*)d_in[10];
  const float* x_edge_pro     = (const float*)d_in[11];
  const float* mask_pep       = (const float*)d_in[12];
  const float* mask_pro       = (const float*)d_in[13];
  const float* E_seq          = (const float*)d_in[14];
  const float* E_ss           = (const float*)d_in[15];
  const float* E_two          = (const float*)d_in[16];
  const float* W_dpep         = (const float*)d_in[17];
  const float* b_dpep         = (const float*)d_in[18];
  const float* W_dpro         = (const float*)d_in[19];
  const float* b_dpro         = (const float*)d_in[20];
  const float* W_ppep         = (const float*)d_in[21];
  const float* b_ppep         = (const float*)d_in[22];
  const float* W_ppro         = (const float*)d_in[23];
  const float* b_ppro         = (const float*)d_in[24];
  const float* Wg_pep1        = (const float*)d_in[25];
  const float* bg_pep1        = (const float*)d_in[26];
  const float* Wg_pep2        = (const float*)d_in[27];
  const float* bg_pep2        = (const float*)d_in[28];
  const float* Wg_pro1        = (const float*)d_in[29];
  const float* bg_pro1        = (const float*)d_in[30];
  const float* Wg_pro2        = (const float*)d_in[31];
  const float* bg_pro2        = (const float*)d_in[32];
  const float* Wt_pep         = (const float*)d_in[33];
  const float* bt_pep         = (const float*)d_in[34];
  const float* Wt_pro         = (const float*)d_in[35];
  const float* bt_pro         = (const float*)d_in[36];

  float* out = (float*)d_out;
  const int BLp = BSZ * LP;   // 2048
  const int BLr = BSZ * LR;   // 16384
  const size_t out_pro_off = (size_t)KH * BSZ * DD * LP;

  // Workspace layout (~117 MB)
  char* w = (char*)d_ws;
  __bf16* encBp  = (__bf16*)w; w += (size_t)BLp * DG * 2;
  __bf16* encBr  = (__bf16*)w; w += (size_t)BLr * DG * 2;
  __bf16* bufATp = (__bf16*)w; w += (size_t)DG * BLp * 2;
  __bf16* bufATr = (__bf16*)w; w += (size_t)DG * BLr * 2;
  __bf16* bufYp  = (__bf16*)w; w += (size_t)BLp * DG * 2;
  __bf16* bufYr  = (__bf16*)w; w += (size_t)BLr * DG * 2;
  __bf16* WppTp  = (__bf16*)w; w += (size_t)DD * 1024 * 2;
  __bf16* WppTr  = (__bf16*)w; w += (size_t)DD * 1024 * 2;
  __bf16* Wg1Tp  = (__bf16*)w; w += (size_t)DG * DG * 2;
  __bf16* Wg2Tp  = (__bf16*)w; w += (size_t)DG * DG * 2;
  __bf16* Wg1Tr  = (__bf16*)w; w += (size_t)DG * DG * 2;
  __bf16* Wg2Tr  = (__bf16*)w; w += (size_t)DG * DG * 2;
  __bf16* WtBp   = (__bf16*)w; w += (size_t)KH * DD * DG * 2;
  __bf16* WtBr   = (__bf16*)w; w += (size_t)KH * DD * DG * 2;
  uint32* packedP = (uint32*)w; w += (size_t)BSZ * (LP / 32) * LP * 4;
  uint32* packedR = (uint32*)w; w += (size_t)BSZ * (LR / 32) * LR * 4;
  float* degP  = (float*)w; w += (size_t)BLp * 4;
  float* degR  = (float*)w; w += (size_t)BLr * 4;
  float* partP = (float*)w; w += (size_t)SPLITK * BLp * DD * 4;
  float* partR = (float*)w; w += (size_t)SPLITK * BLr * DD * 4;

  // 1. weights
  prep_weights<<<dim3(560, 1, 8), 256, 0, stream>>>(
      W_ppep, W_ppro, Wg_pep1, Wg_pep2, Wg_pro1, Wg_pro2, Wt_pep, Wt_pro,
      WppTp, WppTr, Wg1Tp, Wg2Tp, Wg1Tr, Wg2Tr, WtBp, WtBr);
  // 2-3. adjacency prep (degP/degR contiguous -> one memset)
  hipMemsetAsync(degP, 0, (size_t)(BLp + BLr) * sizeof(float), stream);
  prep_pack_merged<<<dim3(4, 32, 17), 256, 0, stream>>>(
      x_edge_pep, x_edge_pro, packedP, packedR, degP, degR);
  // 4. pretrain split-K partials
  pre_gemm<<<dim3((BLp + BLr) / 64, SPLITK), 256, 0, stream>>>(
      x_pretrain_pep, x_pretrain_pro, WppTp, WppTr, partP, partR);
  // 5. encoder (+ pretrain reduce)
  encoder_merged<<<BLp + BLr, 128, 0, stream>>>(
      x_pep, x_ss_pep, x_2_pep, x_dense_pep, W_dpep, b_dpep, mask_pep, partP,
      b_ppep, encBp,
      x_pro, x_ss_pro, x_2_pro, x_dense_pro, W_dpro, b_dpro, mask_pro, partR,
      b_ppro, encBr,
      E_seq, E_ss, E_two);
  // 6-9. GCN (rsqrt folded into epilogues)
  linT_merged<<<dim3((BLp + BLr) / 64, DG / 128), 256, 0, stream>>>(
      Wg1Tp, encBp, degP, bufATp, Wg1Tr, encBr, degR, bufATr);
  agg_merged<<<dim3(160, 9), 256, 0, stream>>>(
      packedP, bufATp, degP, bg_pep1, nullptr, nullptr, bufYp,
      packedR, bufATr, degR, bg_pro1, nullptr, nullptr, bufYr);
  linT_merged<<<dim3((BLp + BLr) / 64, DG / 128), 256, 0, stream>>>(
      Wg2Tp, bufYp, degP, bufATp, Wg2Tr, bufYr, degR, bufATr);
  agg_merged<<<dim3(160, 9), 256, 0, stream>>>(
      packedP, bufATp, degP, bg_pep2, encBp, mask_pep, bufYp,
      packedR, bufATr, degR, bg_pro2, encBr, mask_pro, bufYr);
  // 10. fct
  fct_merged<<<dim3(16, KH, 18), 256, 0, stream>>>(
      WtBp, bt_pep, bufYp, out,
      WtBr, bt_pro, bufYr, out + out_pro_off);
}

// Round 8
// 446.474 us; speedup vs baseline: 1.0319x; 1.0319x over previous
//
#include <hip/hip_runtime.h>
#include <hip/hip_bf16.h>

// Problem constants
#define BSZ 16
#define LP 128
#define LR 1024
#define DD 128
#define DG 640
#define KH 7
#define SPLITK 4

typedef __bf16 bf16x8 __attribute__((ext_vector_type(8)));
typedef __bf16 bf16x4v __attribute__((ext_vector_type(4)));
typedef float f32x4 __attribute__((ext_vector_type(4)));
typedef unsigned int uint32;

// ---------------------------------------------------------------------------
// MFMA core, bf16 A and B: 128(M) x 64(N) tile, BK=64, 4 waves (each 32x64),
// depth-1 prefetch (r6-proven schedule: loads for iter k+1 issued under
// compute(k)). 27.6KB LDS -> 5 blocks/CU; latency hidden by cross-block TLP.
// ---------------------------------------------------------------------------
__device__ __forceinline__ void mfma_core_n64(
    const ushort* __restrict__ Ab, int lda,
    const ushort* __restrict__ Bb, int ldb,
    int m0, int n0, int kStart, int kEnd, f32x4 (&acc)[2][4]) {
  __shared__ __align__(16) ushort As[128 * 72];
  __shared__ __align__(16) ushort Bs[64 * 72];
  int t = threadIdx.x;
  int wave = t >> 6, lane = t & 63;
  int quad = lane >> 4, l16 = lane & 15;
  int wm = wave * 32;
  int r1 = t >> 2, o1 = (t & 3) * 16;

  int4 a0, a1, a2, a3, bb0, bb1;
  auto load_k = [&](int k0) {
    a0 = *(const int4*)(Ab + (size_t)(m0 + r1) * lda + k0 + o1);
    a1 = *(const int4*)(Ab + (size_t)(m0 + r1) * lda + k0 + o1 + 8);
    a2 = *(const int4*)(Ab + (size_t)(m0 + r1 + 64) * lda + k0 + o1);
    a3 = *(const int4*)(Ab + (size_t)(m0 + r1 + 64) * lda + k0 + o1 + 8);
    bb0 = *(const int4*)(Bb + (size_t)(n0 + r1) * ldb + k0 + o1);
    bb1 = *(const int4*)(Bb + (size_t)(n0 + r1) * ldb + k0 + o1 + 8);
  };

  load_k(kStart);
  for (int k0 = kStart; k0 < kEnd; k0 += 64) {
    __syncthreads();   // previous iteration's LDS fully consumed
    *(int4*)&As[r1 * 72 + o1] = a0;
    *(int4*)&As[r1 * 72 + o1 + 8] = a1;
    *(int4*)&As[(r1 + 64) * 72 + o1] = a2;
    *(int4*)&As[(r1 + 64) * 72 + o1 + 8] = a3;
    *(int4*)&Bs[r1 * 72 + o1] = bb0;
    *(int4*)&Bs[r1 * 72 + o1 + 8] = bb1;
    __syncthreads();
    if (k0 + 64 < kEnd) load_k(k0 + 64);  // prefetch under compute
    #pragma unroll
    for (int kc = 0; kc < 2; ++kc) {
      bf16x8 af[2], bfr[4];
      #pragma unroll
      for (int fi = 0; fi < 2; ++fi)
        af[fi] = *(const bf16x8*)&As[(wm + fi * 16 + l16) * 72 + kc * 32 + quad * 8];
      #pragma unroll
      for (int fj = 0; fj < 4; ++fj)
        bfr[fj] = *(const bf16x8*)&Bs[(fj * 16 + l16) * 72 + kc * 32 + quad * 8];
      #pragma unroll
      for (int fi = 0; fi < 2; ++fi)
        #pragma unroll
        for (int fj = 0; fj < 4; ++fj)
          acc[fi][fj] = __builtin_amdgcn_mfma_f32_16x16x32_bf16(
              af[fi], bfr[fj], acc[fi][fj], 0, 0, 0);
    }
  }
}

// ---------------------------------------------------------------------------
// agg core: A built in-register from packed adjacency bits, 128(M)x64(N),
// BK=64, depth-1 prefetch. LDS = 10KB -> 8 blocks/CU (full wave occupancy).
// acc[c][d] += sum_r Ahat[r,c] * Xt[d][bcol + r]
// ---------------------------------------------------------------------------
__device__ __forceinline__ void agg_core_n64(
    const uint32* __restrict__ pb, int L,
    const ushort* __restrict__ Bb, int ldb,
    int m0, int n0, f32x4 (&acc)[2][4]) {
  __shared__ __align__(16) ushort Bs[64 * 72];
  __shared__ uint32 Aw[2][128];
  int t = threadIdx.x;
  int wave = t >> 6, lane = t & 63;
  int quad = lane >> 4, l16 = lane & 15;
  int wm = wave * 32;
  int r1 = t >> 2, o1 = (t & 3) * 16;
  int half = t >> 7, cc = t & 127;

  int4 bb0, bb1;
  uint32 w;
  auto load_k = [&](int k0) {
    bb0 = *(const int4*)(Bb + (size_t)(n0 + r1) * ldb + k0 + o1);
    bb1 = *(const int4*)(Bb + (size_t)(n0 + r1) * ldb + k0 + o1 + 8);
    w = pb[(size_t)((k0 >> 5) + half) * L + m0 + cc];
  };

  load_k(0);
  for (int k0 = 0; k0 < L; k0 += 64) {
    __syncthreads();
    *(int4*)&Bs[r1 * 72 + o1] = bb0;
    *(int4*)&Bs[r1 * 72 + o1 + 8] = bb1;
    Aw[half][cc] = w;
    __syncthreads();
    if (k0 + 64 < L) load_k(k0 + 64);  // prefetch under compute
    #pragma unroll
    for (int kc = 0; kc < 2; ++kc) {
      bf16x8 af[2], bfr[4];
      #pragma unroll
      for (int fj = 0; fj < 4; ++fj)
        bfr[fj] = *(const bf16x8*)&Bs[(fj * 16 + l16) * 72 + kc * 32 + quad * 8];
      #pragma unroll
      for (int fi = 0; fi < 2; ++fi) {
        uint32 bits = (Aw[kc][wm + fi * 16 + l16] >> (quad * 8)) & 0xffu;
        int4 p;
        p.x = (int)((((bits >> 0) & 1) ? 0x3F80u : 0u) | (((bits >> 1) & 1) ? 0x3F800000u : 0u));
        p.y = (int)((((bits >> 2) & 1) ? 0x3F80u : 0u) | (((bits >> 3) & 1) ? 0x3F800000u : 0u));
        p.z = (int)((((bits >> 4) & 1) ? 0x3F80u : 0u) | (((bits >> 5) & 1) ? 0x3F800000u : 0u));
        p.w = (int)((((bits >> 6) & 1) ? 0x3F80u : 0u) | (((bits >> 7) & 1) ? 0x3F800000u : 0u));
        af[fi] = *(bf16x8*)&p;
      }
      #pragma unroll
      for (int fi = 0; fi < 2; ++fi)
        #pragma unroll
        for (int fj = 0; fj < 4; ++fj)
          acc[fi][fj] = __builtin_amdgcn_mfma_f32_16x16x32_bf16(
              af[fi], bfr[fj], acc[fi][fj], 0, 0, 0);
    }
  }
}

// ---------------------------------------------------------------------------
// MFMA core, f32 A (converted to bf16 during staging), 64(M)x128(N), BK=64,
// depth-1 prefetch. M64 doubles pre_gemm's grid (1152 blocks, 4.5/CU).
// ---------------------------------------------------------------------------
__device__ __forceinline__ void mfma_core_f32_m64(
    const float* __restrict__ Af, int lda,
    const ushort* __restrict__ Bb, int ldb,
    int m0, int kStart, int kEnd, f32x4 (&acc)[2][4]) {
  __shared__ __align__(16) ushort As[64 * 72];
  __shared__ __align__(16) ushort Bs[128 * 72];
  int t = threadIdx.x;
  int wave = t >> 6, lane = t & 63;
  int quad = lane >> 4, l16 = lane & 15;
  int wm = (wave >> 1) * 32, wn = (wave & 1) * 64;
  int r1 = t >> 2, o1 = (t & 3) * 16;

  int4 b00, b01, b10, b11;
  float4 af32[4];

  auto load_k = [&](int k0) {
    b00 = *(const int4*)(Bb + (size_t)r1 * ldb + k0 + o1);
    b01 = *(const int4*)(Bb + (size_t)r1 * ldb + k0 + o1 + 8);
    b10 = *(const int4*)(Bb + (size_t)(r1 + 64) * ldb + k0 + o1);
    b11 = *(const int4*)(Bb + (size_t)(r1 + 64) * ldb + k0 + o1 + 8);
    #pragma unroll
    for (int s = 0; s < 4; ++s) {
      int idx = t + s * 256;
      int row = idx >> 4, c4 = (idx & 15) * 4;
      af32[s] = *(const float4*)(Af + (size_t)(m0 + row) * lda + k0 + c4);
    }
  };

  load_k(kStart);
  for (int k0 = kStart; k0 < kEnd; k0 += 64) {
    __syncthreads();
    #pragma unroll
    for (int s = 0; s < 4; ++s) {
      int idx = t + s * 256;
      int row = idx >> 4, c4 = (idx & 15) * 4;
      ushort4 u; __bf16 h;
      h = (__bf16)af32[s].x; u.x = *(ushort*)&h;
      h = (__bf16)af32[s].y; u.y = *(ushort*)&h;
      h = (__bf16)af32[s].z; u.z = *(ushort*)&h;
      h = (__bf16)af32[s].w; u.w = *(ushort*)&h;
      *(ushort4*)&As[row * 72 + c4] = u;
    }
    *(int4*)&Bs[r1 * 72 + o1] = b00;
    *(int4*)&Bs[r1 * 72 + o1 + 8] = b01;
    *(int4*)&Bs[(r1 + 64) * 72 + o1] = b10;
    *(int4*)&Bs[(r1 + 64) * 72 + o1 + 8] = b11;
    __syncthreads();
    if (k0 + 64 < kEnd) load_k(k0 + 64);  // prefetch under compute
    #pragma unroll
    for (int kc = 0; kc < 2; ++kc) {
      bf16x8 af[2], bfr[4];
      #pragma unroll
      for (int fi = 0; fi < 2; ++fi)
        af[fi] = *(const bf16x8*)&As[(wm + fi * 16 + l16) * 72 + kc * 32 + quad * 8];
      #pragma unroll
      for (int fj = 0; fj < 4; ++fj)
        bfr[fj] = *(const bf16x8*)&Bs[(wn + fj * 16 + l16) * 72 + kc * 32 + quad * 8];
      #pragma unroll
      for (int fi = 0; fi < 2; ++fi)
        #pragma unroll
        for (int fj = 0; fj < 4; ++fj)
          acc[fi][fj] = __builtin_amdgcn_mfma_f32_16x16x32_bf16(
              af[fi], bfr[fj], acc[fi][fj], 0, 0, 0);
    }
  }
}

// ---------------------------------------------------------------------------
// prep_all: weight conversions/transposes AND adjacency packing in ONE 1D
// dispatch (fewer launch gaps). No deg atomics: degree is derived from the
// packed bits later (encoder popc). Block ranges:
//   [0,256)      WppT transposes  (2 x 128 tiles of 1024x128)
//   [256,1856)   Wg transposes    (4 x 400 tiles of 640x640)
//   [1856,2976)  WtB f32->bf16    (2 x 560 chunks)
//   [2976,5024)  pro pack         (b=u>>7, rw=(u&127)>>2, c=(u&3)*256+t)
//   [5024,5088)  pep pack         (b=u>>2, rw=u&3, c=t<128)
// ---------------------------------------------------------------------------
__device__ __forceinline__ void tr_tile(const float* __restrict__ src,
                                        __bf16* __restrict__ dst,
                                        int R, int C, int cb, int rb, int t) {
  __shared__ float T[32][33];
  int r0 = rb * 32, c0 = cb * 32;
  #pragma unroll
  for (int s = 0; s < 4; ++s) {
    int idx = t + s * 256;
    int r = idx >> 5, c = idx & 31;
    T[r][c] = src[(size_t)(r0 + r) * C + c0 + c];
  }
  __syncthreads();
  #pragma unroll
  for (int s = 0; s < 4; ++s) {
    int idx = t + s * 256;
    int c = idx >> 5, r = idx & 31;
    dst[(size_t)(c0 + c) * R + r0 + r] = (__bf16)T[r][c];
  }
}

__device__ __forceinline__ void pack_col(const float* __restrict__ adjB,
                                         uint32* __restrict__ packed,
                                         int L, int b, int rw, int c) {
  uint32 w = 0;
  int rbase = rw * 32;
  #pragma unroll 8
  for (int j = 0; j < 32; ++j) {
    float a = adjB[(size_t)(rbase + j) * L + c];
    if (a != 0.f || (rbase + j) == c) w |= (1u << j);
  }
  packed[((size_t)b * (L >> 5) + rw) * L + c] = w;
}

__global__ __launch_bounds__(256) void prep_all(
    const float* __restrict__ Wppep, const float* __restrict__ Wppro,
    const float* __restrict__ Wg1p, const float* __restrict__ Wg2p,
    const float* __restrict__ Wg1r, const float* __restrict__ Wg2r,
    const float* __restrict__ Wtp, const float* __restrict__ Wtr,
    const float* __restrict__ adjP, const float* __restrict__ adjR,
    __bf16* __restrict__ WppTp, __bf16* __restrict__ WppTr,
    __bf16* __restrict__ Wg1Tp, __bf16* __restrict__ Wg2Tp,
    __bf16* __restrict__ Wg1Tr, __bf16* __restrict__ Wg2Tr,
    __bf16* __restrict__ WtBp, __bf16* __restrict__ WtBr,
    uint32* __restrict__ packedP, uint32* __restrict__ packedR) {
  int g = blockIdx.x, t = threadIdx.x;
  if (g < 256) {
    int zi = g >> 7, bx = g & 127;
    tr_tile(zi ? Wppro : Wppep, zi ? WppTr : WppTp, 1024, 128, bx % 4, bx / 4, t);
  } else if (g < 1856) {
    int u = g - 256;
    int zi = u / 400, bx = u % 400;
    const float* src = (zi == 0) ? Wg1p : (zi == 1) ? Wg2p : (zi == 2) ? Wg1r : Wg2r;
    __bf16* dst = (zi == 0) ? Wg1Tp : (zi == 1) ? Wg2Tp : (zi == 2) ? Wg1Tr : Wg2Tr;
    tr_tile(src, dst, 640, 640, bx % 20, bx / 20, t);
  } else if (g < 2976) {
    int u = g - 1856;
    int zi = u / 560, bx = u % 560;
    const float* src = zi ? Wtr : Wtp;
    __bf16* dst = zi ? WtBr : WtBp;
    int i = bx * 256 + t;  // < 143360 float4s
    float4 v = ((const float4*)src)[i];
    bf16x4v o;
    o.x = (__bf16)v.x; o.y = (__bf16)v.y; o.z = (__bf16)v.z; o.w = (__bf16)v.w;
    ((bf16x4v*)dst)[i] = o;
  } else if (g < 5024) {
    int u = g - 2976;
    int b = u >> 7, rem = u & 127;
    int rw = rem >> 2, c = (rem & 3) * 256 + t;
    pack_col(adjR + (size_t)b * LR * LR, packedR, LR, b, rw, c);
  } else {
    int u = g - 5024;
    if (t >= LP) return;
    pack_col(adjP + (size_t)(u >> 2) * LP * LP, packedP, LP, u >> 2, u & 3, t);
  }
}

// ---------------------------------------------------------------------------
// pre_gemm merged (split-K pretrain partials): grid (288, SPLITK).
// bx<32: pep m-block bx (64 rows each); else pro m-block bx-32. by = k-slice.
// ---------------------------------------------------------------------------
__global__ __launch_bounds__(256) void pre_gemm(
    const float* __restrict__ XpP, const float* __restrict__ XpR,
    const __bf16* __restrict__ WppTp, const __bf16* __restrict__ WppTr,
    float* __restrict__ partP, float* __restrict__ partR) {
  int bx = blockIdx.x, s = blockIdx.y;
  int pep = bx < (BSZ * LP / 64);
  int m0 = (pep ? bx : bx - BSZ * LP / 64) * 64;
  const float* A = pep ? XpP : XpR;
  const ushort* B = (const ushort*)(pep ? WppTp : WppTr);
  int BL = pep ? BSZ * LP : BSZ * LR;
  float* part = (pep ? partP : partR) + (size_t)s * BL * DD;

  f32x4 acc[2][4];
  #pragma unroll
  for (int i = 0; i < 2; ++i)
    #pragma unroll
    for (int j = 0; j < 4; ++j) acc[i][j] = (f32x4){0.f, 0.f, 0.f, 0.f};
  mfma_core_f32_m64(A, 1024, B, 1024, m0, s * (1024 / SPLITK),
                    (s + 1) * (1024 / SPLITK), acc);

  int t = threadIdx.x;
  int wave = t >> 6, lane = t & 63;
  int quad = lane >> 4, l16 = lane & 15;
  int wm = (wave >> 1) * 32, wn = (wave & 1) * 64;
  #pragma unroll
  for (int fi = 0; fi < 2; ++fi)
    #pragma unroll
    for (int r = 0; r < 4; ++r) {
      int m = m0 + wm + fi * 16 + quad * 4 + r;
      #pragma unroll
      for (int fj = 0; fj < 4; ++fj) {
        int n = wn + fj * 16 + l16;
        part[(size_t)m * DD + n] = acc[fi][fj][r];
      }
    }
}

// ---------------------------------------------------------------------------
// Encoder merged: embeddings + dense matmul + pretrain-partial reduce
// + dinv from packed-bit popcount (replaces memset+atomicAdd+rsqrt pass;
// packed words already include the self-loop bit, so deg is identical).
// grid (BLp + BLr, 128 threads)
// ---------------------------------------------------------------------------
__global__ __launch_bounds__(128) void encoder_merged(
    const int* __restrict__ xsP, const int* __restrict__ xssP,
    const int* __restrict__ x2P, const float* __restrict__ xdP,
    const float* __restrict__ WdP, const float* __restrict__ bdP,
    const float* __restrict__ maskP, const float* __restrict__ partP,
    const float* __restrict__ bppP, __bf16* __restrict__ encP,
    const uint32* __restrict__ packedP, float* __restrict__ dinvP,
    const int* __restrict__ xsR, const int* __restrict__ xssR,
    const int* __restrict__ x2R, const float* __restrict__ xdR,
    const float* __restrict__ WdR, const float* __restrict__ bdR,
    const float* __restrict__ maskR, const float* __restrict__ partR,
    const float* __restrict__ bppR, __bf16* __restrict__ encR,
    const uint32* __restrict__ packedR, float* __restrict__ dinvR,
    const float* __restrict__ Eseq, const float* __restrict__ Ess,
    const float* __restrict__ Etwo) {
  int gw = blockIdx.x;
  int t = threadIdx.x;
  int pep = gw < BSZ * LP;
  int row = pep ? gw : gw - BSZ * LP;
  int L = pep ? LP : LR;
  int BL = pep ? BSZ * LP : BSZ * LR;
  int Kd = pep ? 3 : 23;
  const int* xs = pep ? xsP : xsR;
  const int* xss = pep ? xssP : xssR;
  const int* x2 = pep ? x2P : x2R;
  const float* xd = pep ? xdP : xdR;
  const float* Wd = pep ? WdP : WdR;
  const float* bd = pep ? bdP : bdR;
  const float* mask = pep ? maskP : maskR;
  const float* part = pep ? partP : partR;
  const float* bpp = pep ? bppP : bppR;
  const uint32* packed = pep ? packedP : packedR;
  float* dinv = pep ? dinvP : dinvR;
  __bf16* enc = pep ? encP : encR;

  // dinv from packed popcount: wave 0, lanes 0..nw-1 (nw = L/32)
  int nw = L >> 5;
  int bb = row / L, ccol = row % L;
  uint32 wv = (t < nw) ? packed[((size_t)bb * nw + t) * L + ccol] : 0u;
  int cnt = __popc(wv);
  if (t < 64) {
    #pragma unroll
    for (int off = 16; off >= 1; off >>= 1) cnt += __shfl_down(cnt, off);
    if (t == 0) dinv[row] = rsqrtf((float)cnt);
  }

  float m = mask[row];
  int i0 = xs[row], i1 = xss[row], i2 = x2[row];
  __bf16* e = enc + (size_t)row * DG;
  e[t]        = (__bf16)(Eseq[i0 * DD + t] * m);
  e[DD + t]   = (__bf16)(Ess[i1 * DD + t] * m);
  e[2*DD + t] = (__bf16)(Etwo[i2 * DD + t] * m);
  float acc = bd[t];
  const float* xr = xd + (size_t)row * Kd;
  for (int i = 0; i < Kd; ++i) acc = fmaf(xr[i], Wd[i * DD + t], acc);
  e[3*DD + t] = (__bf16)(acc * m);
  // pretrain reduce -> cols 512..639
  float p = bpp[t];
  #pragma unroll
  for (int s = 0; s < SPLITK; ++s)
    p += part[(size_t)s * BL * DD + (size_t)row * DD + t];
  e[4*DD + t] = (__bf16)(p * m);
}

// ---------------------------------------------------------------------------
// linT merged: bufAT[d][row] = dinv[row] * sum_k src[row][k] * Wg[k][d]
// grid (288, 5): bx<32 pep n-block (64 rows each), else pro. by = m-block (d).
// ---------------------------------------------------------------------------
__global__ __launch_bounds__(256) void linT_merged(
    const __bf16* __restrict__ WgTp, const __bf16* __restrict__ srcP,
    const float* __restrict__ dinvP, __bf16* __restrict__ dstP,
    const __bf16* __restrict__ WgTr, const __bf16* __restrict__ srcR,
    const float* __restrict__ dinvR, __bf16* __restrict__ dstR) {
  int bx = blockIdx.x;
  int pep = bx < (BSZ * LP / 64);
  int n0 = (pep ? bx : bx - BSZ * LP / 64) * 64;
  int m0 = blockIdx.y * 128;
  int BL = pep ? BSZ * LP : BSZ * LR;
  const ushort* A = (const ushort*)(pep ? WgTp : WgTr);
  const ushort* B = (const ushort*)(pep ? srcP : srcR);
  const float* dinv = pep ? dinvP : dinvR;
  __bf16* dst = pep ? dstP : dstR;

  f32x4 acc[2][4];
  #pragma unroll
  for (int i = 0; i < 2; ++i)
    #pragma unroll
    for (int j = 0; j < 4; ++j) acc[i][j] = (f32x4){0.f, 0.f, 0.f, 0.f};
  mfma_core_n64(A, DG, B, DG, m0, n0, 0, DG, acc);

  int t = threadIdx.x;
  int wave = t >> 6, lane = t & 63;
  int quad = lane >> 4, l16 = lane & 15;
  int wm = wave * 32;
  #pragma unroll
  for (int fi = 0; fi < 2; ++fi)
    #pragma unroll
    for (int r = 0; r < 4; ++r) {
      int m = m0 + wm + fi * 16 + quad * 4 + r;
      #pragma unroll
      for (int fj = 0; fj < 4; ++fj) {
        int n = n0 + fj * 16 + l16;
        dst[(size_t)m * BL + n] = (__bf16)(acc[fi][fj][r] * dinv[n]);
      }
    }
}

// ---------------------------------------------------------------------------
// agg merged, XCD-aware grid: (160, 9).
// bx encodes (b = bx/10, n0 = (bx%10)*64). by==0: pep (m0=0); else pro
// m-block by-1. Same-(b,n0) blocks differ by 160 (160%8==0) -> same XCD.
// Y[b,c,d] = relu(dinv*acc + bias[d] (+encE)) * (mask?)
// ---------------------------------------------------------------------------
__global__ __launch_bounds__(256) void agg_merged(
    const uint32* __restrict__ packedP, const __bf16* __restrict__ XtP,
    const float* __restrict__ dinvP, const float* __restrict__ biasP,
    const __bf16* __restrict__ encEP, const float* __restrict__ maskP,
    __bf16* __restrict__ YP,
    const uint32* __restrict__ packedR, const __bf16* __restrict__ XtR,
    const float* __restrict__ dinvR, const float* __restrict__ biasR,
    const __bf16* __restrict__ encER, const float* __restrict__ maskR,
    __bf16* __restrict__ YR) {
  int bx = blockIdx.x;
  int b = bx / 10;
  int n0 = (bx % 10) * 64;
  int pep = (blockIdx.y == 0);
  int L = pep ? LP : LR;
  int BL = BSZ * L;
  int m0 = pep ? 0 : (blockIdx.y - 1) * 128;
  const uint32* pb = (pep ? packedP : packedR) + (size_t)b * (L >> 5) * L;
  const ushort* Bb = (const ushort*)(pep ? XtP : XtR) + (size_t)b * L;
  const float* dinv = pep ? dinvP : dinvR;
  const float* bias = pep ? biasP : biasR;
  const __bf16* encE = pep ? encEP : encER;
  const float* mask = pep ? maskP : maskR;
  __bf16* Y = pep ? YP : YR;

  f32x4 acc[2][4];
  #pragma unroll
  for (int i = 0; i < 2; ++i)
    #pragma unroll
    for (int j = 0; j < 4; ++j) acc[i][j] = (f32x4){0.f, 0.f, 0.f, 0.f};
  agg_core_n64(pb, L, Bb, BL, m0, n0, acc);

  int t = threadIdx.x;
  int wave = t >> 6, lane = t & 63;
  int quad = lane >> 4, l16 = lane & 15;
  int wm = wave * 32;
  int gRow = b * L;
  #pragma unroll
  for (int fi = 0; fi < 2; ++fi)
    #pragma unroll
    for (int r = 0; r < 4; ++r) {
      int m = m0 + wm + fi * 16 + quad * 4 + r;
      int gi = gRow + m;
      float di = dinv[gi];
      float rm = mask ? mask[gi] : 1.f;
      #pragma unroll
      for (int fj = 0; fj < 4; ++fj) {
        int n = n0 + fj * 16 + l16;
        float v = acc[fi][fj][r] * di + bias[n];
        if (encE) v += (float)encE[(size_t)gi * DG + n];
        v = fmaxf(v, 0.f);
        v *= rm;
        Y[(size_t)gi * DG + n] = (__bf16)v;
      }
    }
}

// ---------------------------------------------------------------------------
// fct merged: grid (16, 7, 18). bz<16: pro (b=bz, n0=bx*64 over LR);
// bz>=16: pep (chunk=(bz-16)*16+bx over BLp flattened). out f32.
// ---------------------------------------------------------------------------
__global__ __launch_bounds__(256) void fct_merged(
    const __bf16* __restrict__ WtBp, const float* __restrict__ btp,
    const __bf16* __restrict__ Yp, float* __restrict__ outP,
    const __bf16* __restrict__ WtBr, const float* __restrict__ btr,
    const __bf16* __restrict__ Yr, float* __restrict__ outR) {
  int kh = blockIdx.y;
  int pro = (blockIdx.z < 16);
  const ushort* A;
  const ushort* B;
  const float* bt;
  int n0;
  if (pro) {
    A = (const ushort*)(WtBr + (size_t)kh * DD * DG);
    B = (const ushort*)(Yr + (size_t)blockIdx.z * LR * DG);
    bt = btr;
    n0 = blockIdx.x * 64;
  } else {
    A = (const ushort*)(WtBp + (size_t)kh * DD * DG);
    B = (const ushort*)Yp;
    bt = btp;
    n0 = ((blockIdx.z - 16) * 16 + blockIdx.x) * 64;
  }

  f32x4 acc[2][4];
  #pragma unroll
  for (int i = 0; i < 2; ++i)
    #pragma unroll
    for (int j = 0; j < 4; ++j) acc[i][j] = (f32x4){0.f, 0.f, 0.f, 0.f};
  mfma_core_n64(A, DG, B, DG, 0, n0, 0, DG, acc);

  int t = threadIdx.x;
  int wave = t >> 6, lane = t & 63;
  int quad = lane >> 4, l16 = lane & 15;
  int wm = wave * 32;
  #pragma unroll
  for (int fi = 0; fi < 2; ++fi)
    #pragma unroll
    for (int r = 0; r < 4; ++r) {
      int m = wm + fi * 16 + quad * 4 + r;
      float bb = bt[kh * DD + m];
      #pragma unroll
      for (int fj = 0; fj < 4; ++fj) {
        int n = n0 + fj * 16 + l16;
        float v = fmaxf(acc[fi][fj][r] + bb, 0.f);
        if (pro) {
          outR[((size_t)(kh * BSZ + blockIdx.z) * DD + m) * LR + n] = v;
        } else {
          int b = n >> 7, l = n & 127;
          outP[((size_t)(kh * BSZ + b) * DD + m) * LP + l] = v;
        }
      }
    }
}

// ---------------------------------------------------------------------------
extern "C" void kernel_launch(void* const* d_in, const int* in_sizes, int n_in,
                              void* d_out, int out_size, void* d_ws, size_t ws_size,
                              hipStream_t stream) {
  const int*   x_pep          = (const int*)d_in[0];
  const int*   x_ss_pep       = (const int*)d_in[1];
  const int*   x_2_pep        = (const int*)d_in[2];
  const float* x_dense_pep    = (const float*)d_in[3];
  const float* x_pretrain_pep = (const float*)d_in[4];
  const int*   x_pro          = (const int*)d_in[5];
  const int*   x_ss_pro       = (const int*)d_in[6];
  const int*   x_2_pro        = (const int*)d_in[7];
  const float* x_dense_pro    = (const float*)d_in[8];
  const float* x_pretrain_pro = (const float*)d_in[9];
  const float* x_edge_pep     = (const float*)d_in[10];
  const float* x_edge_pro     = (const float*)d_in[11];
  const float* mask_pep       = (const float*)d_in[12];
  const float* mask_pro       = (const float*)d_in[13];
  const float* E_seq          = (const float*)d_in[14];
  const float* E_ss           = (const float*)d_in[15];
  const float* E_two          = (const float*)d_in[16];
  const float* W_dpep         = (const float*)d_in[17];
  const float* b_dpep         = (const float*)d_in[18];
  const float* W_dpro         = (const float*)d_in[19];
  const float* b_dpro         = (const float*)d_in[20];
  const float* W_ppep         = (const float*)d_in[21];
  const float* b_ppep         = (const float*)d_in[22];
  const float* W_ppro         = (const float*)d_in[23];
  const float* b_ppro         = (const float*)d_in[24];
  const float* Wg_pep1        = (const float*)d_in[25];
  const float* bg_pep1        = (const float*)d_in[26];
  const float* Wg_pep2        = (const float*)d_in[27];
  const float* bg_pep2        = (const float*)d_in[28];
  const float* Wg_pro1        = (const float*)d_in[29];
  const float* bg_pro1        = (const float*)d_in[30];
  const float* Wg_pro2        = (const float*)d_in[31];
  const float* bg_pro2        = (const float*)d_in[32];
  const float* Wt_pep         = (const float*)d_in[33];
  const float* bt_pep         = (const float*)d_in[34];
  const float* Wt_pro         = (const float*)d_in[35];
  const float* bt_pro         = (const float*)d_in[36];

  float* out = (float*)d_out;
  const int BLp = BSZ * LP;   // 2048
  const int BLr = BSZ * LR;   // 16384
  const size_t out_pro_off = (size_t)KH * BSZ * DD * LP;

  // Workspace layout (~117 MB)
  char* w = (char*)d_ws;
  __bf16* encBp  = (__bf16*)w; w += (size_t)BLp * DG * 2;
  __bf16* encBr  = (__bf16*)w; w += (size_t)BLr * DG * 2;
  __bf16* bufATp = (__bf16*)w; w += (size_t)DG * BLp * 2;
  __bf16* bufATr = (__bf16*)w; w += (size_t)DG * BLr * 2;
  __bf16* bufYp  = (__bf16*)w; w += (size_t)BLp * DG * 2;
  __bf16* bufYr  = (__bf16*)w; w += (size_t)BLr * DG * 2;
  __bf16* WppTp  = (__bf16*)w; w += (size_t)DD * 1024 * 2;
  __bf16* WppTr  = (__bf16*)w; w += (size_t)DD * 1024 * 2;
  __bf16* Wg1Tp  = (__bf16*)w; w += (size_t)DG * DG * 2;
  __bf16* Wg2Tp  = (__bf16*)w; w += (size_t)DG * DG * 2;
  __bf16* Wg1Tr  = (__bf16*)w; w += (size_t)DG * DG * 2;
  __bf16* Wg2Tr  = (__bf16*)w; w += (size_t)DG * DG * 2;
  __bf16* WtBp   = (__bf16*)w; w += (size_t)KH * DD * DG * 2;
  __bf16* WtBr   = (__bf16*)w; w += (size_t)KH * DD * DG * 2;
  uint32* packedP = (uint32*)w; w += (size_t)BSZ * (LP / 32) * LP * 4;
  uint32* packedR = (uint32*)w; w += (size_t)BSZ * (LR / 32) * LR * 4;
  float* dinvP = (float*)w; w += (size_t)BLp * 4;
  float* dinvR = (float*)w; w += (size_t)BLr * 4;
  float* partP = (float*)w; w += (size_t)SPLITK * BLp * DD * 4;
  float* partR = (float*)w; w += (size_t)SPLITK * BLr * DD * 4;

  // 1. weights + adjacency pack (single merged dispatch, no atomics)
  prep_all<<<5088, 256, 0, stream>>>(
      W_ppep, W_ppro, Wg_pep1, Wg_pep2, Wg_pro1, Wg_pro2, Wt_pep, Wt_pro,
      x_edge_pep, x_edge_pro,
      WppTp, WppTr, Wg1Tp, Wg2Tp, Wg1Tr, Wg2Tr, WtBp, WtBr,
      packedP, packedR);
  // 2. pretrain split-K partials
  pre_gemm<<<dim3((BLp + BLr) / 64, SPLITK), 256, 0, stream>>>(
      x_pretrain_pep, x_pretrain_pro, WppTp, WppTr, partP, partR);
  // 3. encoder (+ pretrain reduce + dinv from popcount)
  encoder_merged<<<BLp + BLr, 128, 0, stream>>>(
      x_pep, x_ss_pep, x_2_pep, x_dense_pep, W_dpep, b_dpep, mask_pep, partP,
      b_ppep, encBp, packedP, dinvP,
      x_pro, x_ss_pro, x_2_pro, x_dense_pro, W_dpro, b_dpro, mask_pro, partR,
      b_ppro, encBr, packedR, dinvR,
      E_seq, E_ss, E_two);
  // 4-7. GCN
  linT_merged<<<dim3((BLp + BLr) / 64, DG / 128), 256, 0, stream>>>(
      Wg1Tp, encBp, dinvP, bufATp, Wg1Tr, encBr, dinvR, bufATr);
  agg_merged<<<dim3(160, 9), 256, 0, stream>>>(
      packedP, bufATp, dinvP, bg_pep1, nullptr, nullptr, bufYp,
      packedR, bufATr, dinvR, bg_pro1, nullptr, nullptr, bufYr);
  linT_merged<<<dim3((BLp + BLr) / 64, DG / 128), 256, 0, stream>>>(
      Wg2Tp, bufYp, dinvP, bufATp, Wg2Tr, bufYr, dinvR, bufATr);
  agg_merged<<<dim3(160, 9), 256, 0, stream>>>(
      packedP, bufATp, dinvP, bg_pep2, encBp, mask_pep, bufYp,
      packedR, bufATr, dinvR, bg_pro2, encBr, mask_pro, bufYr);
  // 8. fct
  fct_merged<<<dim3(16, KH, 18), 256, 0, stream>>>(
      WtBp, bt_pep, bufYp, out,
      WtBr, bt_pro, bufYr, out + out_pro_off);
}